// Round 5
// baseline (53.147 us; speedup 1.0000x reference)
//
#include <hip/hip_runtime.h>

// Problem constants (B=16384, D=1024, HARD_RATIO=0.3 -> K=4915)
constexpr int B_ROWS = 16384;
constexpr int K_HARD = 4915;           // max(1, int(16384 * 0.3))
constexpr float MARGIN_POS = 0.1f;
constexpr float MARGIN_NEG = 0.8f;

typedef float f32x4 __attribute__((ext_vector_type(4)));

// ---------------------------------------------------------------------------
// Kernel 1: rowwise dot products, one wave per row, 12 loads in flight.
// L3-partitioning experiment: q and d_pos (128 MiB) use normal cached loads
// (should become L3-resident across graph replays); d_neg (64 MiB) uses `nt`
// non-temporal loads so it does not allocate in / pollute the LLC, streaming
// straight from HBM on a parallel path.
// ---------------------------------------------------------------------------
__global__ __launch_bounds__(256, 8) void dot_kernel(
    const float* __restrict__ q,
    const float* __restrict__ dp,
    const float* __restrict__ dn,
    float* __restrict__ out_pos,
    float* __restrict__ out_neg)
{
    const int wave = (blockIdx.x * blockDim.x + threadIdx.x) >> 6;
    const int lane = threadIdx.x & 63;
    const unsigned voff = (unsigned)wave * 4096u + (unsigned)lane * 16u;

    f32x4 q0, q1, q2, q3, p0, p1, p2, p3, n0, n1, n2, n3;
    asm volatile(
        "global_load_dwordx4 %[Q0], %[VO], %[QB] offset:0\n\t"
        "global_load_dwordx4 %[Q1], %[VO], %[QB] offset:1024\n\t"
        "global_load_dwordx4 %[Q2], %[VO], %[QB] offset:2048\n\t"
        "global_load_dwordx4 %[Q3], %[VO], %[QB] offset:3072\n\t"
        "global_load_dwordx4 %[P0], %[VO], %[PB] offset:0\n\t"
        "global_load_dwordx4 %[P1], %[VO], %[PB] offset:1024\n\t"
        "global_load_dwordx4 %[P2], %[VO], %[PB] offset:2048\n\t"
        "global_load_dwordx4 %[P3], %[VO], %[PB] offset:3072\n\t"
        "global_load_dwordx4 %[N0], %[VO], %[NB] offset:0 nt\n\t"
        "global_load_dwordx4 %[N1], %[VO], %[NB] offset:1024 nt\n\t"
        "global_load_dwordx4 %[N2], %[VO], %[NB] offset:2048 nt\n\t"
        "global_load_dwordx4 %[N3], %[VO], %[NB] offset:3072 nt\n\t"
        "s_waitcnt vmcnt(0)"
        : [Q0]"=&v"(q0), [Q1]"=&v"(q1), [Q2]"=&v"(q2), [Q3]"=&v"(q3),
          [P0]"=&v"(p0), [P1]"=&v"(p1), [P2]"=&v"(p2), [P3]"=&v"(p3),
          [N0]"=&v"(n0), [N1]"=&v"(n1), [N2]"=&v"(n2), [N3]"=&v"(n3)
        : [VO]"v"(voff), [QB]"s"(q), [PB]"s"(dp), [NB]"s"(dn)
    );

    f32x4 qa[4] = {q0, q1, q2, q3};
    f32x4 pa[4] = {p0, p1, p2, p3};
    f32x4 na[4] = {n0, n1, n2, n3};

    float sp = 0.f, sn = 0.f;
#pragma unroll
    for (int it = 0; it < 4; ++it) {
#pragma unroll
        for (int c = 0; c < 4; ++c) {
            sp += qa[it][c] * pa[it][c];
            sn += qa[it][c] * na[it][c];
        }
    }
#pragma unroll
    for (int off = 32; off; off >>= 1) {
        sp += __shfl_xor(sp, off);
        sn += __shfl_xor(sn, off);
    }
    if (lane == 0) {
        out_pos[wave] = sp;
        out_neg[wave] = sn;
    }
}

// order-preserving float -> uint32 key (ascending float == ascending uint)
__device__ __forceinline__ unsigned f2key(float f) {
    unsigned u = __float_as_uint(f);
    return (u & 0x80000000u) ? ~u : (u | 0x80000000u);
}
__device__ __forceinline__ float key2f(unsigned k) {
    return __uint_as_float((k & 0x80000000u) ? (k & 0x7FFFFFFFu) : ~k);
}

// ---------------------------------------------------------------------------
// Kernel 2 (fused select + finalize): one 1024-thread block processes BOTH
// sides CONCURRENTLY (16 pos + 16 neg keys per thread, dual LDS histograms;
// wave 0 scans pos bins while wave 1 scans neg bins). Exact k-th order
// statistic via 4-round byte radix-select, then conditional sum with tie
// correction. Writes all 3 outputs.
// ---------------------------------------------------------------------------
__global__ __launch_bounds__(1024) void select_finalize_kernel(
    const float* __restrict__ ws_vals,   // [2*B]: pos then neg
    float* __restrict__ out)             // 3 floats
{
    __shared__ unsigned hist[2][256];
    __shared__ unsigned ebase[2][256];
    __shared__ unsigned s_prefix[2], s_m[2];
    __shared__ float    s_rf[2][16];
    __shared__ unsigned s_rc[2][16];

    const int tid  = threadIdx.x;
    const int lane = tid & 63;
    const int wid  = tid >> 6;

    const float4* vp = (const float4*)ws_vals;              // pos
    const float4* vn = (const float4*)(ws_vals + B_ROWS);   // neg

    unsigned kp[16], kn[16];
#pragma unroll
    for (int j = 0; j < 4; ++j) {
        const float4 a = vp[tid + j * 1024];
        const float4 b = vn[tid + j * 1024];
        kp[4*j+0] = f2key(a.x); kp[4*j+1] = f2key(a.y);
        kp[4*j+2] = f2key(a.z); kp[4*j+3] = f2key(a.w);
        kn[4*j+0] = f2key(b.x); kn[4*j+1] = f2key(b.y);
        kn[4*j+2] = f2key(b.z); kn[4*j+3] = f2key(b.w);
    }

    // target 0-based ascending ranks:
    //   pos: rank N-K (smallest member of top-K largest)
    //   neg: rank K-1 (largest member of bottom-K smallest)
    unsigned m0 = (unsigned)(B_ROWS - K_HARD), pre0 = 0;
    unsigned m1 = (unsigned)(K_HARD - 1),      pre1 = 0;

    for (int r = 0; r < 4; ++r) {
        const unsigned shift = 24 - 8 * r;
        const unsigned pmask = (r == 0) ? 0u : (0xFFFFFFFFu << (32 - 8 * r));
        if (tid < 256) { hist[0][tid] = 0; hist[1][tid] = 0; }
        __syncthreads();
#pragma unroll
        for (int j = 0; j < 16; ++j) {
            if ((kp[j] & pmask) == pre0) atomicAdd(&hist[0][(kp[j] >> shift) & 255u], 1u);
            if ((kn[j] & pmask) == pre1) atomicAdd(&hist[1][(kn[j] >> shift) & 255u], 1u);
        }
        __syncthreads();

        // wave 0 scans side 0, wave 1 scans side 1 (4 bins/lane, shfl_up scan)
        if (wid < 2) {
            const int s = wid;
            const unsigned h0 = hist[s][4*lane+0], h1 = hist[s][4*lane+1];
            const unsigned h2 = hist[s][4*lane+2], h3 = hist[s][4*lane+3];
            const unsigned g = h0 + h1 + h2 + h3;
            unsigned inc = g;
#pragma unroll
            for (int off = 1; off < 64; off <<= 1) {
                const unsigned t = __shfl_up(inc, off);
                if (lane >= off) inc += t;
            }
            const unsigned ex = inc - g;
            ebase[s][4*lane+0] = ex;
            ebase[s][4*lane+1] = ex + h0;
            ebase[s][4*lane+2] = ex + h0 + h1;
            ebase[s][4*lane+3] = ex + h0 + h1 + h2;
        }
        __syncthreads();

        if (tid < 512) {
            const int s = tid >> 8;
            const int b = tid & 255;
            const unsigned mm = s ? m1 : m0;
            const unsigned lo = ebase[s][b];
            const unsigned hi = lo + hist[s][b];
            if (lo <= mm && mm < hi) {      // exactly one bucket per side
                s_prefix[s] = (s ? pre1 : pre0) | ((unsigned)b << shift);
                s_m[s] = mm - lo;
            }
        }
        __syncthreads();
        pre0 = s_prefix[0]; m0 = s_m[0];
        pre1 = s_prefix[1]; m1 = s_m[1];
        // safe: hist/s_prefix next written only after 2+ more syncs
    }

    const unsigned tk0 = pre0, tk1 = pre1;   // exact k-th order statistics
    const float    tv0 = key2f(tk0), tv1 = key2f(tk1);

    float lp = 0.f, ln = 0.f;
    unsigned cp = 0, cn = 0;
#pragma unroll
    for (int j = 0; j < 16; ++j) {
        if (kp[j] > tk0) { lp += fmaxf(key2f(kp[j]) - MARGIN_POS, 0.f); cp++; }
        if (kn[j] < tk1) { ln += fmaxf(MARGIN_NEG - key2f(kn[j]), 0.f); cn++; }
    }
#pragma unroll
    for (int off = 32; off; off >>= 1) {
        lp += __shfl_xor(lp, off);  ln += __shfl_xor(ln, off);
        cp += __shfl_xor(cp, off);  cn += __shfl_xor(cn, off);
    }
    if (lane == 0) {
        s_rf[0][wid] = lp; s_rf[1][wid] = ln;
        s_rc[0][wid] = cp; s_rc[1][wid] = cn;
    }
    __syncthreads();
    if (tid == 0) {
        float tp = 0.f, tn = 0.f;
        unsigned ccp = 0, ccn = 0;
        for (int w = 0; w < 16; ++w) {
            tp += s_rf[0][w]; tn += s_rf[1][w];
            ccp += s_rc[0][w]; ccn += s_rc[1][w];
        }
        const float fp = fmaxf(tv0 - MARGIN_POS, 0.f);
        const float fn = fmaxf(MARGIN_NEG - tv1, 0.f);
        const float LP = (tp + (float)(K_HARD - (int)ccp) * fp) / (float)K_HARD;
        const float LN = (tn + (float)(K_HARD - (int)ccn) * fn) / (float)K_HARD;
        out[0] = LP + LN;
        out[1] = LP;
        out[2] = LN;
    }
}

extern "C" void kernel_launch(void* const* d_in, const int* in_sizes, int n_in,
                              void* d_out, int out_size, void* d_ws, size_t ws_size,
                              hipStream_t stream) {
    const float* q  = (const float*)d_in[0];   // q_neg_proj
    const float* dp = (const float*)d_in[1];   // d_pos
    const float* dn = (const float*)d_in[2];   // d_neg
    float* out = (float*)d_out;                // 3 floats

    float* ws     = (float*)d_ws;
    float* ws_pos = ws;                // [0, B)
    float* ws_neg = ws + B_ROWS;       // [B, 2B)

    // Kernel 1: one wave per row -> 16384 waves -> 4096 blocks x 256
    dot_kernel<<<(B_ROWS * 64) / 256, 256, 0, stream>>>(q, dp, dn, ws_pos, ws_neg);
    // Kernel 2: single block, both sides concurrently + finalize
    select_finalize_kernel<<<1, 1024, 0, stream>>>(ws_pos, out);
}

// Round 6
// 47.350 us; speedup vs baseline: 1.1224x; 1.1224x over previous
//
#include <hip/hip_runtime.h>

// Problem constants (B=16384, D=1024, HARD_RATIO=0.3 -> K=4915)
constexpr int B_ROWS = 16384;
constexpr int K_HARD = 4915;           // max(1, int(16384 * 0.3))
constexpr float MARGIN_POS = 0.1f;
constexpr float MARGIN_NEG = 0.8f;

typedef float f32x4 __attribute__((ext_vector_type(4)));

// ---------------------------------------------------------------------------
// Kernel 1: rowwise dot products, one wave per row, 12 loads in flight.
// q/d_pos cached; d_neg `nt` (non-temporal). Also resets the finalize ticket.
// Measured across R1-R5: this access mix is pinned at ~4.5 TB/s effective
// read (~92% of the chip's best measured read-heavy kernel) regardless of
// issue structure -> treat as at-ceiling, leave untouched.
// ---------------------------------------------------------------------------
__global__ __launch_bounds__(256, 8) void dot_kernel(
    const float* __restrict__ q,
    const float* __restrict__ dp,
    const float* __restrict__ dn,
    float* __restrict__ out_pos,
    float* __restrict__ out_neg,
    int* __restrict__ ticket)
{
    const int wave = (blockIdx.x * blockDim.x + threadIdx.x) >> 6;
    const int lane = threadIdx.x & 63;

    if (blockIdx.x == 0 && threadIdx.x == 0) {
        __hip_atomic_store(ticket, 0, __ATOMIC_RELAXED, __HIP_MEMORY_SCOPE_AGENT);
    }

    const unsigned voff = (unsigned)wave * 4096u + (unsigned)lane * 16u;

    f32x4 q0, q1, q2, q3, p0, p1, p2, p3, n0, n1, n2, n3;
    asm volatile(
        "global_load_dwordx4 %[Q0], %[VO], %[QB] offset:0\n\t"
        "global_load_dwordx4 %[Q1], %[VO], %[QB] offset:1024\n\t"
        "global_load_dwordx4 %[Q2], %[VO], %[QB] offset:2048\n\t"
        "global_load_dwordx4 %[Q3], %[VO], %[QB] offset:3072\n\t"
        "global_load_dwordx4 %[P0], %[VO], %[PB] offset:0\n\t"
        "global_load_dwordx4 %[P1], %[VO], %[PB] offset:1024\n\t"
        "global_load_dwordx4 %[P2], %[VO], %[PB] offset:2048\n\t"
        "global_load_dwordx4 %[P3], %[VO], %[PB] offset:3072\n\t"
        "global_load_dwordx4 %[N0], %[VO], %[NB] offset:0 nt\n\t"
        "global_load_dwordx4 %[N1], %[VO], %[NB] offset:1024 nt\n\t"
        "global_load_dwordx4 %[N2], %[VO], %[NB] offset:2048 nt\n\t"
        "global_load_dwordx4 %[N3], %[VO], %[NB] offset:3072 nt\n\t"
        "s_waitcnt vmcnt(0)"
        : [Q0]"=&v"(q0), [Q1]"=&v"(q1), [Q2]"=&v"(q2), [Q3]"=&v"(q3),
          [P0]"=&v"(p0), [P1]"=&v"(p1), [P2]"=&v"(p2), [P3]"=&v"(p3),
          [N0]"=&v"(n0), [N1]"=&v"(n1), [N2]"=&v"(n2), [N3]"=&v"(n3)
        : [VO]"v"(voff), [QB]"s"(q), [PB]"s"(dp), [NB]"s"(dn)
    );

    f32x4 qa[4] = {q0, q1, q2, q3};
    f32x4 pa[4] = {p0, p1, p2, p3};
    f32x4 na[4] = {n0, n1, n2, n3};

    float sp = 0.f, sn = 0.f;
#pragma unroll
    for (int it = 0; it < 4; ++it) {
#pragma unroll
        for (int c = 0; c < 4; ++c) {
            sp += qa[it][c] * pa[it][c];
            sn += qa[it][c] * na[it][c];
        }
    }
#pragma unroll
    for (int off = 32; off; off >>= 1) {
        sp += __shfl_xor(sp, off);
        sn += __shfl_xor(sn, off);
    }
    if (lane == 0) {
        out_pos[wave] = sp;
        out_neg[wave] = sn;
    }
}

// order-preserving float -> uint32 key (ascending float == ascending uint)
__device__ __forceinline__ unsigned f2key(float f) {
    unsigned u = __float_as_uint(f);
    return (u & 0x80000000u) ? ~u : (u | 0x80000000u);
}
__device__ __forceinline__ float key2f(unsigned k) {
    return __uint_as_float((k & 0x80000000u) ? (k & 0x7FFFFFFFu) : ~k);
}

// ---------------------------------------------------------------------------
// Kernel 2: per-side select + last-block finalize. 2 blocks x 1024 threads;
// block 0 = positives (k-th largest, relu(v-0.1)), block 1 = negatives
// (k-th smallest, relu(0.8-v)). Exact k-th order statistic via 4-round byte
// radix-select (wave-parallel bucket scan), conditional sum + tie correction.
// Each block agent-atomically stores its loss to out[1+side]; the SECOND
// block to bump the ticket computes out[0] = out[1] + out[2] (2-addend float
// add is commutative -> deterministic regardless of which block is last).
// ---------------------------------------------------------------------------
__global__ __launch_bounds__(1024) void select_kernel(
    const float* __restrict__ ws_vals,   // [2*B]: pos then neg
    float* __restrict__ out,             // 3 floats
    int* __restrict__ ticket)
{
    __shared__ unsigned hist[256];
    __shared__ unsigned ebase[256];
    __shared__ unsigned s_prefix, s_m;
    __shared__ float    s_rf[16];
    __shared__ unsigned s_rc[16];

    const int side = blockIdx.x;         // 0 = pos, 1 = neg
    const int tid  = threadIdx.x;
    const int lane = tid & 63;
    const int wid  = tid >> 6;

    const float4* v4 = (const float4*)(ws_vals + side * B_ROWS);

    unsigned key[16];
#pragma unroll
    for (int j = 0; j < 4; ++j) {
        const float4 a = v4[tid + j * 1024];
        key[4*j+0] = f2key(a.x); key[4*j+1] = f2key(a.y);
        key[4*j+2] = f2key(a.z); key[4*j+3] = f2key(a.w);
    }

    // target 0-based ascending rank:
    //   pos: rank N-K (smallest member of top-K largest)
    //   neg: rank K-1 (largest member of bottom-K smallest)
    unsigned m = side ? (unsigned)(K_HARD - 1) : (unsigned)(B_ROWS - K_HARD);
    unsigned prefix = 0;

    for (int r = 0; r < 4; ++r) {
        const unsigned shift = 24 - 8 * r;
        const unsigned pmask = (r == 0) ? 0u : (0xFFFFFFFFu << (32 - 8 * r));
        if (tid < 256) hist[tid] = 0;
        __syncthreads();
#pragma unroll
        for (int j = 0; j < 16; ++j)
            if ((key[j] & pmask) == prefix)
                atomicAdd(&hist[(key[j] >> shift) & 255u], 1u);
        __syncthreads();

        // wave 0: parallel exclusive prefix over 256 bins (4 bins/lane)
        if (wid == 0) {
            const unsigned h0 = hist[4*lane+0], h1 = hist[4*lane+1];
            const unsigned h2 = hist[4*lane+2], h3 = hist[4*lane+3];
            const unsigned g = h0 + h1 + h2 + h3;
            unsigned inc = g;
#pragma unroll
            for (int off = 1; off < 64; off <<= 1) {
                const unsigned t = __shfl_up(inc, off);
                if (lane >= off) inc += t;
            }
            const unsigned ex = inc - g;
            ebase[4*lane+0] = ex;
            ebase[4*lane+1] = ex + h0;
            ebase[4*lane+2] = ex + h0 + h1;
            ebase[4*lane+3] = ex + h0 + h1 + h2;
        }
        __syncthreads();

        if (tid < 256) {
            const unsigned lo = ebase[tid];
            const unsigned hi = lo + hist[tid];
            if (lo <= m && m < hi) {         // exactly one bucket satisfies
                s_prefix = prefix | ((unsigned)tid << shift);
                s_m = m - lo;
            }
        }
        __syncthreads();
        prefix = s_prefix;
        m = s_m;
        // safe: hist/s_prefix next written only after 2+ more syncs
    }

    const unsigned tkey = prefix;            // exact k-th order statistic bits
    const float    tval = key2f(tkey);

    float lsum = 0.f;
    unsigned cnt = 0;
#pragma unroll
    for (int j = 0; j < 16; ++j) {
        const bool sel = side ? (key[j] < tkey) : (key[j] > tkey);
        if (sel) {
            const float v = key2f(key[j]);
            lsum += side ? fmaxf(MARGIN_NEG - v, 0.f)
                         : fmaxf(v - MARGIN_POS, 0.f);
            cnt++;
        }
    }
#pragma unroll
    for (int off = 32; off; off >>= 1) {
        lsum += __shfl_xor(lsum, off);
        cnt  += __shfl_xor(cnt, off);
    }
    if (lane == 0) { s_rf[wid] = lsum; s_rc[wid] = cnt; }
    __syncthreads();

    if (tid == 0) {
        float tot = 0.f;
        unsigned c = 0;
        for (int w = 0; w < 16; ++w) { tot += s_rf[w]; c += s_rc[w]; }
        const float ft = side ? fmaxf(MARGIN_NEG - tval, 0.f)
                              : fmaxf(tval - MARGIN_POS, 0.f);
        const float loss = (tot + (float)(K_HARD - (int)c) * ft) / (float)K_HARD;

        // publish own loss (agent scope: blocks may be on different XCDs)
        __hip_atomic_store(&out[1 + side], loss,
                           __ATOMIC_RELEASE, __HIP_MEMORY_SCOPE_AGENT);
        const int t = __hip_atomic_fetch_add(ticket, 1,
                           __ATOMIC_ACQ_REL, __HIP_MEMORY_SCOPE_AGENT);
        if (t == 1) {  // second (last) block finishes the sum
            const float lp = __hip_atomic_load(&out[1],
                                __ATOMIC_ACQUIRE, __HIP_MEMORY_SCOPE_AGENT);
            const float ln = __hip_atomic_load(&out[2],
                                __ATOMIC_ACQUIRE, __HIP_MEMORY_SCOPE_AGENT);
            __hip_atomic_store(&out[0], lp + ln,
                               __ATOMIC_RELAXED, __HIP_MEMORY_SCOPE_AGENT);
        }
    }
}

extern "C" void kernel_launch(void* const* d_in, const int* in_sizes, int n_in,
                              void* d_out, int out_size, void* d_ws, size_t ws_size,
                              hipStream_t stream) {
    const float* q  = (const float*)d_in[0];   // q_neg_proj
    const float* dp = (const float*)d_in[1];   // d_pos
    const float* dn = (const float*)d_in[2];   // d_neg
    float* out = (float*)d_out;                // 3 floats

    float* ws     = (float*)d_ws;
    float* ws_pos = ws;                        // [0, B)
    float* ws_neg = ws + B_ROWS;               // [B, 2B)
    int*   ticket = (int*)(ws + 2 * B_ROWS);   // finalize ticket (reset by dot)

    // Kernel 1: one wave per row -> 16384 waves -> 4096 blocks x 256
    dot_kernel<<<(B_ROWS * 64) / 256, 256, 0, stream>>>(q, dp, dn, ws_pos, ws_neg, ticket);
    // Kernel 2: 2 blocks (one per side), last block finalizes out[0]
    select_kernel<<<2, 1024, 0, stream>>>(ws_pos, out, ticket);
}